// Round 1
// baseline (2044.966 us; speedup 1.0000x reference)
//
#include <hip/hip_runtime.h>
#include <math.h>

// Problem constants (MultiHeadAttention: B=2, L=2048, D=768, H=12, HD=64)
#define B_  2
#define L_  2048
#define D_  768
#define H_  12
#define HD_ 64
#define M_  (B_*L_)          // 4096 rows for the GEMMs
#define N3_ (3*D_)           // 2304
#define OUT_ELEMS ((size_t)B_*L_*D_)   // 3145728

static constexpr float kScale = 0.022097086912079608f;  // 1/sqrt(2048) (NOTE: ref divides by sqrt(L))

// ============================ GEMM (fp32, 128x128 tile, 8x8/thread) ============================
#define BM 128
#define BN 128
#define BK 16

__global__ __launch_bounds__(256) void gemm_bias_kernel(
    const float* __restrict__ A, const float* __restrict__ Bm,
    const float* __restrict__ bias, float* __restrict__ C,
    int M, int N, int K, int mode,
    float* __restrict__ qp, float* __restrict__ kp, float* __restrict__ vp)
{
  __shared__ float As[BK][BM + 4];   // transposed: As[kk][m]; +4 pad breaks stride-128 banks
  __shared__ float Bs[BK][BN + 4];

  const int tid = threadIdx.x;
  const int bm = blockIdx.y * BM;
  const int bn = blockIdx.x * BN;
  const int tx = tid & 15;
  const int ty = tid >> 4;

  // global load mapping
  const int arow = tid >> 1;          // 0..127
  const int akq  = (tid & 1) * 8;     // 0 or 8
  const int bnq  = tx * 8;            // 0..120 (row ty of B tile)

  float acc[8][8];
#pragma unroll
  for (int i = 0; i < 8; ++i)
#pragma unroll
    for (int j = 0; j < 8; ++j) acc[i][j] = 0.f;

  const float* Ap = A + (size_t)(bm + arow) * K + akq;
  const float* Bp = Bm + (size_t)ty * N + bn + bnq;

  for (int k0 = 0; k0 < K; k0 += BK) {
    float4 a0 = *(const float4*)(Ap + k0);
    float4 a1 = *(const float4*)(Ap + k0 + 4);
    float4 b0 = *(const float4*)(Bp + (size_t)k0 * N);
    float4 b1 = *(const float4*)(Bp + (size_t)k0 * N + 4);
    As[akq + 0][arow] = a0.x; As[akq + 1][arow] = a0.y;
    As[akq + 2][arow] = a0.z; As[akq + 3][arow] = a0.w;
    As[akq + 4][arow] = a1.x; As[akq + 5][arow] = a1.y;
    As[akq + 6][arow] = a1.z; As[akq + 7][arow] = a1.w;
    *(float4*)&Bs[ty][bnq]     = b0;
    *(float4*)&Bs[ty][bnq + 4] = b1;
    __syncthreads();
#pragma unroll
    for (int kk = 0; kk < BK; ++kk) {
      float av[8], bv[8];
      // split into two 64-halves: lanes read float4 at stride-4 addresses -> <=2-way bank alias
      *(float4*)&av[0] = *(const float4*)&As[kk][ty * 4];
      *(float4*)&av[4] = *(const float4*)&As[kk][64 + ty * 4];
      *(float4*)&bv[0] = *(const float4*)&Bs[kk][tx * 4];
      *(float4*)&bv[4] = *(const float4*)&Bs[kk][64 + tx * 4];
#pragma unroll
      for (int i = 0; i < 8; ++i)
#pragma unroll
        for (int j = 0; j < 8; ++j) acc[i][j] += av[i] * bv[j];
    }
    __syncthreads();
  }

  // epilogue: thread owns rows {bm+ty*4+i, bm+64+ty*4+i} x cols {bn+tx*4+j, bn+64+tx*4+j}
  float bj[8];
#pragma unroll
  for (int j = 0; j < 4; ++j) {
    bj[j]     = bias[bn + tx * 4 + j];
    bj[j + 4] = bias[bn + 64 + tx * 4 + j];
  }

#pragma unroll
  for (int i = 0; i < 8; ++i) {
    const int m = bm + ((i < 4) ? (ty * 4 + i) : (64 + ty * 4 + (i - 4)));
    float4 oA, oB;
    oA.x = acc[i][0] + bj[0]; oA.y = acc[i][1] + bj[1];
    oA.z = acc[i][2] + bj[2]; oA.w = acc[i][3] + bj[3];
    oB.x = acc[i][4] + bj[4]; oB.y = acc[i][5] + bj[5];
    oB.z = acc[i][6] + bj[6]; oB.w = acc[i][7] + bj[7];
    if (mode == 0) {
      float* crow = C + (size_t)m * N;
      *(float4*)(crow + bn + tx * 4)      = oA;
      *(float4*)(crow + bn + 64 + tx * 4) = oB;
    } else {
      // split qkv: n -> (which, h, d); BN=128 tiles never straddle the 768 boundaries
      const int bi = m >> 11;           // batch
      const int li = m & (L_ - 1);      // position
      const int nA = bn + tx * 4;
      const int which = nA / D_;        // uniform across both halves of this tile
      float* dstT = (which == 0) ? qp : (which == 1) ? kp : vp;
      const int rA = nA - which * D_;
      const int rB = rA + 64;
      const int hA = rA >> 6, dA = rA & 63;
      const int hB = rB >> 6, dB = rB & 63;
      *(float4*)(dstT + (((size_t)(bi * H_ + hA)) * L_ + li) * HD_ + dA) = oA;
      *(float4*)(dstT + (((size_t)(bi * H_ + hB)) * L_ + li) * HD_ + dB) = oB;
    }
  }
}

// ============================ RoPE (in-place on q and k, [B,H,L,64]) ============================
__global__ __launch_bounds__(256) void rope_kernel(float* __restrict__ qp, float* __restrict__ kp)
{
  const int gid  = blockIdx.x * 256 + threadIdx.x;
  const int row  = gid >> 6;         // 0 .. 2*B*H*L-1 (q rows then k rows)
  const int lane = gid & 63;         // d within head; wave-aligned
  const int BHL  = B_ * H_ * L_;     // 49152
  float* base = (row < BHL) ? qp : kp;
  const int r = (row < BHL) ? row : row - BHL;
  const int l = r & (L_ - 1);        // position (layout [B][H][L])
  float* p = base + (size_t)r * HD_ + lane;
  float val = *p;
  float part = __shfl_xor(val, 32, 64);      // pair d <-> d^32 lives in same wave
  const int i = lane & 31;
  // inv_freq = 10000^(-i/32) = 2^(-i*log2(10000)/32)
  const float invf = exp2f(-(float)i * 0.415241011860920f);
  const float theta = (float)l * invf;
  float sv, cv;
  sincosf(theta, &sv, &cv);
  const float rot = (lane < 32) ? -part : part;  // rotate_half: [-x2, x1]
  *p = val * cv + rot * sv;
}

// ============================ Fused causal attention + probs write ============================
// block: 256 threads, 32 q-rows; K streamed in 64-row LDS tiles.
// Pass 1: softmax denominator (no max-subtract: |scores| <~ 4, exp is safe).
// Pass 2: recompute scores -> normalized probs (staged in LDS, coalesced global write) + PV.
#define TQ 32
#define TK 64

__global__ __launch_bounds__(256) void attn_kernel(
    const float* __restrict__ qm, const float* __restrict__ km,
    const float* __restrict__ vm, float* __restrict__ probs,
    float* __restrict__ attn)
{
  __shared__ float Qs[TQ][68];
  __shared__ float Ks[TK][68];
  __shared__ float Vs[TK][68];
  __shared__ float Ps[TQ][68];
  __shared__ float Linv[TQ];

  const int tid = threadIdx.x;
  const int bh  = blockIdx.y;              // 0..23
  const int q0  = blockIdx.x * TQ;
  const int bb  = bh / H_;
  const int hh  = bh - bb * H_;

  const float* qbase = qm + ((size_t)bh * L_ + q0) * HD_;
  const float* kbase = km + (size_t)bh * L_ * HD_;
  const float* vbase = vm + (size_t)bh * L_ * HD_;

  {  // load Q tile (32 x 64)
    const int row = tid >> 3, off = (tid & 7) * 8;
    const float* src = qbase + row * HD_ + off;
    *(float4*)&Qs[row][off]     = *(const float4*)(src);
    *(float4*)&Qs[row][off + 4] = *(const float4*)(src + 4);
  }

  const int qi  = tid >> 3;          // 0..31 : q row within tile
  const int ks  = tid & 7;           // 0..7  : k sub-slot / d sub-slot
  const int myq = q0 + qi;
  const int ktiles = (q0 + TQ + TK - 1) / TK;
  const int lrow = tid >> 2, loff = (tid & 3) * 16;   // K/V tile cooperative-load mapping

  // ---------------- pass 1: denominators ----------------
  float l = 0.f;
  for (int kt = 0; kt < ktiles; ++kt) {
    const int k0 = kt * TK;
    {
      const float* src = kbase + (size_t)(k0 + lrow) * HD_ + loff;
      *(float4*)&Ks[lrow][loff]      = *(const float4*)(src);
      *(float4*)&Ks[lrow][loff + 4]  = *(const float4*)(src + 4);
      *(float4*)&Ks[lrow][loff + 8]  = *(const float4*)(src + 8);
      *(float4*)&Ks[lrow][loff + 12] = *(const float4*)(src + 12);
    }
    __syncthreads();
#pragma unroll
    for (int j = 0; j < 8; ++j) {
      const int kl = ks + 8 * j;     // consecutive lanes -> consecutive Ks rows (bank-friendly)
      float s = 0.f;
#pragma unroll
      for (int dd = 0; dd < HD_; dd += 4) {
        const float4 qv = *(const float4*)&Qs[qi][dd];
        const float4 kv = *(const float4*)&Ks[kl][dd];
        s += qv.x * kv.x + qv.y * kv.y + qv.z * kv.z + qv.w * kv.w;
      }
      if (k0 + kl <= myq) l += __expf(s * kScale);
    }
    __syncthreads();
  }
  // reduce over the 8 lanes sharing qi (they are consecutive lanes in one wave)
  l += __shfl_xor(l, 1, 64);
  l += __shfl_xor(l, 2, 64);
  l += __shfl_xor(l, 4, 64);
  if (ks == 0) Linv[qi] = 1.f / l;
  __syncthreads();
  const float linv = Linv[qi];

  // ---------------- pass 2: probs + PV ----------------
  float accv[8] = {0.f, 0.f, 0.f, 0.f, 0.f, 0.f, 0.f, 0.f};
  float* prow = probs + ((size_t)bh * L_ + myq) * L_;

  for (int kt = 0; kt < ktiles; ++kt) {
    const int k0 = kt * TK;
    {
      const float* srck = kbase + (size_t)(k0 + lrow) * HD_ + loff;
      const float* srcv = vbase + (size_t)(k0 + lrow) * HD_ + loff;
      *(float4*)&Ks[lrow][loff]      = *(const float4*)(srck);
      *(float4*)&Ks[lrow][loff + 4]  = *(const float4*)(srck + 4);
      *(float4*)&Ks[lrow][loff + 8]  = *(const float4*)(srck + 8);
      *(float4*)&Ks[lrow][loff + 12] = *(const float4*)(srck + 12);
      *(float4*)&Vs[lrow][loff]      = *(const float4*)(srcv);
      *(float4*)&Vs[lrow][loff + 4]  = *(const float4*)(srcv + 4);
      *(float4*)&Vs[lrow][loff + 8]  = *(const float4*)(srcv + 8);
      *(float4*)&Vs[lrow][loff + 12] = *(const float4*)(srcv + 12);
    }
    __syncthreads();
#pragma unroll
    for (int j = 0; j < 8; ++j) {
      const int kl = ks + 8 * j;
      float s = 0.f;
#pragma unroll
      for (int dd = 0; dd < HD_; dd += 4) {
        const float4 qv = *(const float4*)&Qs[qi][dd];
        const float4 kv = *(const float4*)&Ks[kl][dd];
        s += qv.x * kv.x + qv.y * kv.y + qv.z * kv.z + qv.w * kv.w;
      }
      Ps[qi][kl] = (k0 + kl <= myq) ? __expf(s * kScale) * linv : 0.f;
    }
    __syncthreads();
    {  // coalesced probs tile write (8 lanes x 32B = 256B contiguous per row)
      const float4 p0 = *(const float4*)&Ps[qi][ks * 8];
      const float4 p1 = *(const float4*)&Ps[qi][ks * 8 + 4];
      float* dst = prow + k0 + ks * 8;
      *(float4*)dst       = p0;
      *(float4*)(dst + 4) = p1;
    }
    // PV accumulate: thread owns (qi, d = ks*8..ks*8+7)
#pragma unroll
    for (int kl = 0; kl < TK; ++kl) {
      const float p = Ps[qi][kl];
      const float4 v0 = *(const float4*)&Vs[kl][ks * 8];
      const float4 v1 = *(const float4*)&Vs[kl][ks * 8 + 4];
      accv[0] += p * v0.x; accv[1] += p * v0.y; accv[2] += p * v0.z; accv[3] += p * v0.w;
      accv[4] += p * v1.x; accv[5] += p * v1.y; accv[6] += p * v1.z; accv[7] += p * v1.w;
    }
    __syncthreads();
  }

  // zero-fill masked columns beyond the last processed k-tile
  {
    const float4 z = make_float4(0.f, 0.f, 0.f, 0.f);
    for (int c0 = ktiles * TK; c0 < L_; c0 += TK) {
      *(float4*)(prow + c0 + ks * 8)     = z;
      *(float4*)(prow + c0 + ks * 8 + 4) = z;
    }
  }

  // attn output in [B, L, D] layout (ready for out-proj GEMM)
  {
    float* dst = attn + ((size_t)bb * L_ + myq) * D_ + hh * HD_ + ks * 8;
    *(float4*)dst       = make_float4(accv[0], accv[1], accv[2], accv[3]);
    *(float4*)(dst + 4) = make_float4(accv[4], accv[5], accv[6], accv[7]);
  }
}

// ============================ launcher ============================
extern "C" void kernel_launch(void* const* d_in, const int* in_sizes, int n_in,
                              void* d_out, int out_size, void* d_ws, size_t ws_size,
                              hipStream_t stream)
{
  const float* x     = (const float*)d_in[0];   // [B,L,D]
  const float* w_qkv = (const float*)d_in[1];   // [D,3D]
  const float* b_qkv = (const float*)d_in[2];   // [3D]
  const float* w_out = (const float*)d_in[3];   // [D,D]
  const float* b_out = (const float*)d_in[4];   // [D]

  float* out   = (float*)d_out;                 // [B,L,D]
  float* probs = out + OUT_ELEMS;               // [B,H,L,L]

  // workspace: q,k,v in [B,H,L,64] + attn in [B,L,D]  (4 x 12.58 MB = 50.3 MB)
  float* ws    = (float*)d_ws;
  float* qw    = ws;
  float* kw    = ws + OUT_ELEMS;
  float* vw    = ws + 2 * OUT_ELEMS;
  float* attnw = ws + 3 * OUT_ELEMS;

  // 1) QKV projection + bias + head-split into q/k/v
  gemm_bias_kernel<<<dim3(N3_ / BN, M_ / BM), 256, 0, stream>>>(
      x, w_qkv, b_qkv, nullptr, M_, N3_, D_, 1, qw, kw, vw);

  // 2) RoPE in place on q and k
  rope_kernel<<<(2 * B_ * H_ * L_ * HD_) / 256, 256, 0, stream>>>(qw, kw);

  // 3) fused causal attention: writes probs (d_out tail) + attn (ws)
  attn_kernel<<<dim3(L_ / TQ, B_ * H_), 256, 0, stream>>>(qw, kw, vw, probs, attnw);

  // 4) output projection + bias
  gemm_bias_kernel<<<dim3(D_ / BN, M_ / BM), 256, 0, stream>>>(
      attnw, w_out, b_out, out, M_, D_, D_, 0, nullptr, nullptr, nullptr);
}

// Round 2
// 832.659 us; speedup vs baseline: 2.4559x; 2.4559x over previous
//
#include <hip/hip_runtime.h>
#include <math.h>

// Problem constants (MultiHeadAttention: B=2, L=2048, D=768, H=12, HD=64)
#define B_  2
#define L_  2048
#define D_  768
#define H_  12
#define HD_ 64
#define M_  (B_*L_)          // 4096 rows for the GEMMs
#define N3_ (3*D_)           // 2304
#define OUT_ELEMS ((size_t)B_*L_*D_)   // 3145728

static constexpr float kScale = 0.022097086912079608f;  // 1/sqrt(2048) (ref divides by sqrt(L))

typedef __attribute__((ext_vector_type(8))) short short8;
typedef __attribute__((ext_vector_type(4))) float f32x4;

__device__ __forceinline__ unsigned short f2bf(float f) {
  union { float f; unsigned u; } v; v.f = f;
  unsigned r = v.u + 0x7FFFu + ((v.u >> 16) & 1u);   // round-to-nearest-even
  return (unsigned short)(r >> 16);
}
__device__ __forceinline__ float bf2f(unsigned short b) {
  union { unsigned u; float f; } v; v.u = ((unsigned)b) << 16;
  return v.f;
}

// ============================ GEMM (fp32, 128x128 tile, 8x8/thread) ============================
#define BM 128
#define BN 128
#define BK 16

__global__ __launch_bounds__(256) void gemm_bias_kernel(
    const float* __restrict__ A, const float* __restrict__ Bm,
    const float* __restrict__ bias, float* __restrict__ C,
    int M, int N, int K, int mode,
    unsigned short* __restrict__ qp, unsigned short* __restrict__ kp,
    unsigned short* __restrict__ vp)
{
  __shared__ float As[BK][BM + 4];   // transposed: As[kk][m]
  __shared__ float Bs[BK][BN + 4];

  const int tid = threadIdx.x;
  const int bm = blockIdx.y * BM;
  const int bn = blockIdx.x * BN;
  const int tx = tid & 15;
  const int ty = tid >> 4;

  const int arow = tid >> 1;
  const int akq  = (tid & 1) * 8;
  const int bnq  = tx * 8;

  float acc[8][8];
#pragma unroll
  for (int i = 0; i < 8; ++i)
#pragma unroll
    for (int j = 0; j < 8; ++j) acc[i][j] = 0.f;

  const float* Ap = A + (size_t)(bm + arow) * K + akq;
  const float* Bp = Bm + (size_t)ty * N + bn + bnq;

  for (int k0 = 0; k0 < K; k0 += BK) {
    float4 a0 = *(const float4*)(Ap + k0);
    float4 a1 = *(const float4*)(Ap + k0 + 4);
    float4 b0 = *(const float4*)(Bp + (size_t)k0 * N);
    float4 b1 = *(const float4*)(Bp + (size_t)k0 * N + 4);
    As[akq + 0][arow] = a0.x; As[akq + 1][arow] = a0.y;
    As[akq + 2][arow] = a0.z; As[akq + 3][arow] = a0.w;
    As[akq + 4][arow] = a1.x; As[akq + 5][arow] = a1.y;
    As[akq + 6][arow] = a1.z; As[akq + 7][arow] = a1.w;
    *(float4*)&Bs[ty][bnq]     = b0;
    *(float4*)&Bs[ty][bnq + 4] = b1;
    __syncthreads();
#pragma unroll
    for (int kk = 0; kk < BK; ++kk) {
      float av[8], bv[8];
      *(float4*)&av[0] = *(const float4*)&As[kk][ty * 4];
      *(float4*)&av[4] = *(const float4*)&As[kk][64 + ty * 4];
      *(float4*)&bv[0] = *(const float4*)&Bs[kk][tx * 4];
      *(float4*)&bv[4] = *(const float4*)&Bs[kk][64 + tx * 4];
#pragma unroll
      for (int i = 0; i < 8; ++i)
#pragma unroll
        for (int j = 0; j < 8; ++j) acc[i][j] += av[i] * bv[j];
    }
    __syncthreads();
  }

  float bj[8];
#pragma unroll
  for (int j = 0; j < 4; ++j) {
    bj[j]     = bias[bn + tx * 4 + j];
    bj[j + 4] = bias[bn + 64 + tx * 4 + j];
  }

#pragma unroll
  for (int i = 0; i < 8; ++i) {
    const int m = bm + ((i < 4) ? (ty * 4 + i) : (64 + ty * 4 + (i - 4)));
    float4 oA, oB;
    oA.x = acc[i][0] + bj[0]; oA.y = acc[i][1] + bj[1];
    oA.z = acc[i][2] + bj[2]; oA.w = acc[i][3] + bj[3];
    oB.x = acc[i][4] + bj[4]; oB.y = acc[i][5] + bj[5];
    oB.z = acc[i][6] + bj[6]; oB.w = acc[i][7] + bj[7];
    if (mode == 0) {
      float* crow = C + (size_t)m * N;
      *(float4*)(crow + bn + tx * 4)      = oA;
      *(float4*)(crow + bn + 64 + tx * 4) = oB;
    } else {
      // split qkv: n -> (which, h, d), write bf16 [B,H,L,64]
      const int bi = m >> 11;
      const int li = m & (L_ - 1);
      const int nA = bn + tx * 4;
      const int which = nA / D_;        // uniform for this tile (128 | 768)
      unsigned short* dstT = (which == 0) ? qp : (which == 1) ? kp : vp;
      const int rA = nA - which * D_;
      const int rB = rA + 64;
      const int hA = rA >> 6, dA = rA & 63;
      const int hB = rB >> 6, dB = rB & 63;
      uint2 pA, pB;
      pA.x = (unsigned)f2bf(oA.x) | ((unsigned)f2bf(oA.y) << 16);
      pA.y = (unsigned)f2bf(oA.z) | ((unsigned)f2bf(oA.w) << 16);
      pB.x = (unsigned)f2bf(oB.x) | ((unsigned)f2bf(oB.y) << 16);
      pB.y = (unsigned)f2bf(oB.z) | ((unsigned)f2bf(oB.w) << 16);
      *(uint2*)(dstT + (((size_t)(bi * H_ + hA)) * L_ + li) * HD_ + dA) = pA;
      *(uint2*)(dstT + (((size_t)(bi * H_ + hB)) * L_ + li) * HD_ + dB) = pB;
    }
  }
}

// ============================ RoPE (in-place on bf16 q and k, [B,H,L,64]) ============================
__global__ __launch_bounds__(256) void rope_kernel(unsigned short* __restrict__ qb,
                                                   unsigned short* __restrict__ kb)
{
  const int gid  = blockIdx.x * 256 + threadIdx.x;
  const int row  = gid >> 6;
  const int lane = gid & 63;
  const int BHL  = B_ * H_ * L_;
  unsigned short* base = (row < BHL) ? qb : kb;
  const int r = (row < BHL) ? row : row - BHL;
  const int l = r & (L_ - 1);
  unsigned short* p = base + (size_t)r * HD_ + lane;
  float val = bf2f(*p);
  float part = __shfl_xor(val, 32, 64);
  const int i = lane & 31;
  const float invf = exp2f(-(float)i * 0.415241011860920f);  // 10000^(-i/32)
  const float theta = (float)l * invf;
  float sv, cv;
  sincosf(theta, &sv, &cv);
  const float rot = (lane < 32) ? -part : part;
  *p = f2bf(val * cv + rot * sv);
}

// ============================ V transpose: [B,H,L,64] -> [B,H,64,L] (bf16) ============================
__global__ __launch_bounds__(256) void vtrans_kernel(const unsigned short* __restrict__ vb,
                                                     unsigned short* __restrict__ vt)
{
  const int bh = blockIdx.y;
  const int l0 = blockIdx.x * 64;
  const int t = threadIdx.x;
  const int l = l0 + (t >> 2);
  const int d0 = (t & 3) * 16;
  const unsigned short* src = vb + ((size_t)bh * L_ + l) * HD_ + d0;
  unsigned short tmp[16];
  *(uint4*)tmp       = *(const uint4*)src;
  *(uint4*)(tmp + 8) = *(const uint4*)(src + 8);
  unsigned short* dst = vt + (size_t)bh * HD_ * L_ + l;
#pragma unroll
  for (int j = 0; j < 16; ++j)
    dst[(size_t)(d0 + j) * L_] = tmp[j];
}

// ============================ Fused causal attention (MFMA bf16) ============================
// Block: 4 waves x 16 q-rows = 64 q rows. K tiles of 64.
// Pass 1: QK mfma -> row sums (registers only). Pass 2: QK mfma -> fp32 probs store +
// bf16 P via per-wave LDS (C-layout -> A-layout) -> PV mfma.
__global__ __launch_bounds__(256) void attn_mfma_kernel(
    const unsigned short* __restrict__ qb, const unsigned short* __restrict__ kb,
    const unsigned short* __restrict__ vt, float* __restrict__ probs,
    float* __restrict__ attn)
{
  __shared__ unsigned short Ks[64][72];      // [kpos][d]
  __shared__ unsigned short Vs[64][72];      // [d][kpos]  (from vt)
  __shared__ unsigned short Pb[4][16][72];   // per-wave P tile [qrow][kpos]

  const int tid  = threadIdx.x;
  const int w    = tid >> 6;
  const int lane = tid & 63;
  const int m16  = lane & 15;
  const int quad = lane >> 4;

  const int bh = blockIdx.y;
  const int qt = (int)gridDim.x - 1 - (int)blockIdx.x;   // big tiles first
  const int q0 = qt * 64;
  const int bb = bh / H_;
  const int hh = bh - bb * H_;
  const int ktiles = qt + 1;
  const int qrow_base = q0 + w * 16;

  const unsigned short* kbase = kb + (size_t)bh * L_ * HD_;
  const unsigned short* vbase = vt + (size_t)bh * HD_ * L_;

  // Q fragments: A[m=lane&15][k=quad*8+j]
  const unsigned short* qp = qb + ((size_t)bh * L_ + qrow_base + m16) * HD_ + quad * 8;
  const short8 qf0 = *(const short8*)(qp);
  const short8 qf1 = *(const short8*)(qp + 32);

  const int srow = tid >> 2;
  const int scol = (tid & 3) * 16;

  // ---------------- pass 1: row sums ----------------
  float lsum[4] = {0.f, 0.f, 0.f, 0.f};
  for (int kt = 0; kt < ktiles; ++kt) {
    const int k0 = kt * 64;
    __syncthreads();
    {
      const unsigned short* src = kbase + (size_t)(k0 + srow) * HD_ + scol;
      *(uint4*)&Ks[srow][scol]     = *(const uint4*)src;
      *(uint4*)&Ks[srow][scol + 8] = *(const uint4*)(src + 8);
    }
    __syncthreads();
#pragma unroll
    for (int cg = 0; cg < 4; ++cg) {
      const short8 b0 = *(const short8*)&Ks[cg * 16 + m16][quad * 8];
      const short8 b1 = *(const short8*)&Ks[cg * 16 + m16][32 + quad * 8];
      f32x4 s = {0.f, 0.f, 0.f, 0.f};
      s = __builtin_amdgcn_mfma_f32_16x16x32_bf16(qf0, b0, s, 0, 0, 0);
      s = __builtin_amdgcn_mfma_f32_16x16x32_bf16(qf1, b1, s, 0, 0, 0);
      const int kcol = k0 + cg * 16 + m16;
#pragma unroll
      for (int r2 = 0; r2 < 4; ++r2) {
        const int qrow = qrow_base + quad * 4 + r2;
        const float e = __expf(s[r2] * kScale);
        lsum[r2] += (kcol <= qrow) ? e : 0.f;
      }
    }
  }
  float linv[4];
#pragma unroll
  for (int r2 = 0; r2 < 4; ++r2) {
    float v = lsum[r2];
    v += __shfl_xor(v, 1, 64);
    v += __shfl_xor(v, 2, 64);
    v += __shfl_xor(v, 4, 64);
    v += __shfl_xor(v, 8, 64);
    linv[r2] = 1.f / v;
  }

  // ---------------- pass 2: probs + PV ----------------
  f32x4 oacc[4];
#pragma unroll
  for (int og = 0; og < 4; ++og) { oacc[og][0]=0.f; oacc[og][1]=0.f; oacc[og][2]=0.f; oacc[og][3]=0.f; }

  for (int kt = 0; kt < ktiles; ++kt) {
    const int k0 = kt * 64;
    __syncthreads();
    {
      const unsigned short* srck = kbase + (size_t)(k0 + srow) * HD_ + scol;
      *(uint4*)&Ks[srow][scol]     = *(const uint4*)srck;
      *(uint4*)&Ks[srow][scol + 8] = *(const uint4*)(srck + 8);
      const unsigned short* srcv = vbase + (size_t)srow * L_ + k0 + scol;
      *(uint4*)&Vs[srow][scol]     = *(const uint4*)srcv;
      *(uint4*)&Vs[srow][scol + 8] = *(const uint4*)(srcv + 8);
    }
    __syncthreads();
#pragma unroll
    for (int cg = 0; cg < 4; ++cg) {
      const short8 b0 = *(const short8*)&Ks[cg * 16 + m16][quad * 8];
      const short8 b1 = *(const short8*)&Ks[cg * 16 + m16][32 + quad * 8];
      f32x4 s = {0.f, 0.f, 0.f, 0.f};
      s = __builtin_amdgcn_mfma_f32_16x16x32_bf16(qf0, b0, s, 0, 0, 0);
      s = __builtin_amdgcn_mfma_f32_16x16x32_bf16(qf1, b1, s, 0, 0, 0);
      const int kcol = k0 + cg * 16 + m16;
#pragma unroll
      for (int r2 = 0; r2 < 4; ++r2) {
        const int qrow = qrow_base + quad * 4 + r2;
        const float p = (kcol <= qrow) ? __expf(s[r2] * kScale) * linv[r2] : 0.f;
        probs[((size_t)bh * L_ + qrow) * L_ + kcol] = p;
        Pb[w][quad * 4 + r2][cg * 16 + m16] = f2bf(p);
      }
    }
    // PV: A = P (per-wave LDS), B = V^T rows
    const short8 pa0 = *(const short8*)&Pb[w][m16][quad * 8];
    const short8 pa1 = *(const short8*)&Pb[w][m16][32 + quad * 8];
#pragma unroll
    for (int og = 0; og < 4; ++og) {
      const short8 v0 = *(const short8*)&Vs[og * 16 + m16][quad * 8];
      const short8 v1 = *(const short8*)&Vs[og * 16 + m16][32 + quad * 8];
      oacc[og] = __builtin_amdgcn_mfma_f32_16x16x32_bf16(pa0, v0, oacc[og], 0, 0, 0);
      oacc[og] = __builtin_amdgcn_mfma_f32_16x16x32_bf16(pa1, v1, oacc[og], 0, 0, 0);
    }
  }

  // zero-fill masked probs columns beyond processed tiles
  {
    const float4 z4 = make_float4(0.f, 0.f, 0.f, 0.f);
#pragma unroll
    for (int r2 = 0; r2 < 4; ++r2) {
      float* pr = probs + ((size_t)bh * L_ + qrow_base + quad * 4 + r2) * L_;
      for (int c0 = ktiles * 64; c0 < L_; c0 += 64)
        *(float4*)(pr + c0 + m16 * 4) = z4;
    }
  }

  // O epilogue -> attn [B,L,D] fp32 (C-layout: row=quad*4+r, col=og*16+m16)
#pragma unroll
  for (int og = 0; og < 4; ++og)
#pragma unroll
    for (int r2 = 0; r2 < 4; ++r2)
      attn[((size_t)bb * L_ + qrow_base + quad * 4 + r2) * D_ + hh * HD_ + og * 16 + m16] =
          oacc[og][r2];
}

// ============================ launcher ============================
extern "C" void kernel_launch(void* const* d_in, const int* in_sizes, int n_in,
                              void* d_out, int out_size, void* d_ws, size_t ws_size,
                              hipStream_t stream)
{
  const float* x     = (const float*)d_in[0];
  const float* w_qkv = (const float*)d_in[1];
  const float* b_qkv = (const float*)d_in[2];
  const float* w_out = (const float*)d_in[3];
  const float* b_out = (const float*)d_in[4];

  float* out   = (float*)d_out;
  float* probs = out + OUT_ELEMS;

  const size_t NE = (size_t)B_ * H_ * L_ * HD_;     // 3145728 per tensor
  unsigned short* qbw = (unsigned short*)d_ws;      // bf16 q [B,H,L,64]
  unsigned short* kbw = qbw + NE;                   // bf16 k
  unsigned short* vbw = kbw + NE;                   // bf16 v (natural)
  unsigned short* vtw = vbw + NE;                   // bf16 v^T [B,H,64,L]
  float* attnw = (float*)(vtw + NE);                // fp32 attn [B,L,D]

  // 1) QKV projection + bias -> bf16 q/k/v head-split
  gemm_bias_kernel<<<dim3(N3_ / BN, M_ / BM), 256, 0, stream>>>(
      x, w_qkv, b_qkv, nullptr, M_, N3_, D_, 1, qbw, kbw, vbw);

  // 2) RoPE in place (bf16)
  rope_kernel<<<(2 * B_ * H_ * L_ * HD_) / 256, 256, 0, stream>>>(qbw, kbw);

  // 3) V transpose for PV B-operand reads
  vtrans_kernel<<<dim3(L_ / 64, B_ * H_), 256, 0, stream>>>(vbw, vtw);

  // 4) fused causal attention (MFMA): probs + attn
  attn_mfma_kernel<<<dim3(L_ / 64, B_ * H_), 256, 0, stream>>>(qbw, kbw, vtw, probs, attnw);

  // 5) output projection + bias (fp32)
  gemm_bias_kernel<<<dim3(D_ / BN, M_ / BM), 256, 0, stream>>>(
      attnw, w_out, b_out, out, M_, D_, D_, 0, nullptr, nullptr, nullptr);
}

// Round 3
// 567.619 us; speedup vs baseline: 3.6027x; 1.4669x over previous
//
#include <hip/hip_runtime.h>
#include <math.h>

// Problem constants (MultiHeadAttention: B=2, L=2048, D=768, H=12, HD=64)
#define B_  2
#define L_  2048
#define D_  768
#define H_  12
#define HD_ 64
#define M_  (B_*L_)          // 4096 rows for the GEMMs
#define N3_ (3*D_)           // 2304
#define OUT_ELEMS ((size_t)B_*L_*D_)   // 3145728

static constexpr float kScale = 0.022097086912079608f;  // 1/sqrt(2048) (ref divides by sqrt(L))
static constexpr float kLog2_10000_div32 = 0.415241011860920f;

typedef __attribute__((ext_vector_type(8))) short short8;
typedef __attribute__((ext_vector_type(4))) float f32x4;

__device__ __forceinline__ unsigned short f2bf(float f) {
  union { float f; unsigned u; } v; v.f = f;
  unsigned r = v.u + 0x7FFFu + ((v.u >> 16) & 1u);   // round-to-nearest-even
  return (unsigned short)(r >> 16);
}

__device__ __forceinline__ void async_cp16(const void* g, void* l) {
  __builtin_amdgcn_global_load_lds((const __attribute__((address_space(1))) void*)g,
                                   (__attribute__((address_space(3))) void*)l, 16, 0, 0);
}

// ===================== convert fp32 -> bf16 (straight) =====================
__global__ __launch_bounds__(256) void bf16conv_kernel(const float* __restrict__ in,
                                                       unsigned short* __restrict__ out)
{
  const int idx = blockIdx.x * 256 + threadIdx.x;
  const float* src = in + (size_t)idx * 8;
  float4 a = *(const float4*)src;
  float4 b = *(const float4*)(src + 4);
  unsigned short t[8];
  t[0] = f2bf(a.x); t[1] = f2bf(a.y); t[2] = f2bf(a.z); t[3] = f2bf(a.w);
  t[4] = f2bf(b.x); t[5] = f2bf(b.y); t[6] = f2bf(b.z); t[7] = f2bf(b.w);
  *(uint4*)(out + (size_t)idx * 8) = *(uint4*)t;
}

// ===================== weight transpose+convert: fp32 [K][N] -> bf16 [N][K] =====================
__global__ __launch_bounds__(256) void wtrans_kernel(const float* __restrict__ in,
                                                     unsigned short* __restrict__ out,
                                                     int K, int N)
{
  __shared__ __align__(16) unsigned short T[64][72];
  const int n0 = blockIdx.x * 64;
  const int k0 = blockIdx.y * 64;
  const int tid = threadIdx.x;
  const int row = tid >> 2;          // 0..63
  const int col = (tid & 3) * 16;    // 0,16,32,48
  {
    const float* src = in + (size_t)(k0 + row) * N + n0 + col;
    unsigned short tmp[16];
#pragma unroll
    for (int j = 0; j < 16; j += 4) {
      float4 v = *(const float4*)(src + j);
      tmp[j] = f2bf(v.x); tmp[j + 1] = f2bf(v.y); tmp[j + 2] = f2bf(v.z); tmp[j + 3] = f2bf(v.w);
    }
    *(uint4*)&T[row][col]     = *(uint4*)tmp;       // T[k][n]
    *(uint4*)&T[row][col + 8] = *(uint4*)(tmp + 8);
  }
  __syncthreads();
  unsigned short tmp[16];
#pragma unroll
  for (int j = 0; j < 16; ++j) tmp[j] = T[col + j][row];   // gather k-run for fixed n=row
  unsigned short* dst = out + (size_t)(n0 + row) * K + k0 + col;
  *(uint4*)dst       = *(uint4*)tmp;
  *(uint4*)(dst + 8) = *(uint4*)(tmp + 8);
}

// ===================== V transpose bf16: [B,H,L,64] -> [B,H,64,L] =====================
__global__ __launch_bounds__(256) void vtrans_kernel(const unsigned short* __restrict__ vb,
                                                     unsigned short* __restrict__ vt)
{
  __shared__ __align__(16) unsigned short T[64][72];
  const int bh = blockIdx.y;
  const int l0 = blockIdx.x * 64;
  const int tid = threadIdx.x;
  const int row = tid >> 2;
  const int col = (tid & 3) * 16;
  {
    const unsigned short* src = vb + ((size_t)bh * L_ + l0 + row) * HD_ + col;
    *(uint4*)&T[row][col]     = *(const uint4*)src;        // T[l][d]
    *(uint4*)&T[row][col + 8] = *(const uint4*)(src + 8);
  }
  __syncthreads();
  unsigned short tmp[16];
#pragma unroll
  for (int j = 0; j < 16; ++j) tmp[j] = T[col + j][row];   // l-run for fixed d=row
  unsigned short* dst = vt + ((size_t)bh * HD_ + row) * L_ + l0 + col;
  *(uint4*)dst       = *(uint4*)tmp;
  *(uint4*)(dst + 8) = *(uint4*)(tmp + 8);
}

// ===================== bf16 MFMA GEMM: C[M][N] = A[M][K] * Bt[N][K]^T + bias =====================
// 128x128 tile, BK=32, 4 waves each computing a 64x64 quadrant (4x4 of 16x16x32 mfma).
// Staging via global_load_lds(16B) with chunk^=(row&3) XOR swizzle (conflict-free ds_read_b128).
// mode 0: fp32 C store.  mode 1: QKV -> bf16 q/k/v head-split with FUSED RoPE on q,k.
__global__ __launch_bounds__(256) void gemm_mfma_kernel(
    const unsigned short* __restrict__ A, const unsigned short* __restrict__ Bt,
    const float* __restrict__ bias, float* __restrict__ C,
    int M, int N, int K, int mode,
    unsigned short* __restrict__ qp, unsigned short* __restrict__ kp,
    unsigned short* __restrict__ vp)
{
  __shared__ __align__(16) unsigned short As[128 * 32];
  __shared__ __align__(16) unsigned short Bs[128 * 32];

  const int tid  = threadIdx.x;
  const int w    = tid >> 6;
  const int lane = tid & 63;
  const int m16  = lane & 15;
  const int quad = lane >> 4;
  const int wr   = w & 1;        // row half of quadrant
  const int wc   = w >> 1;       // col half

  const int bm = blockIdx.y * 128;
  const int bn = blockIdx.x * 128;

  // staging: wave w covers slots [w*128, w*128+128); slot s -> row s/4, stored chunk s%4,
  // fetched data chunk (s%4)^(row&3)
  const int s0 = w * 128 + lane;
  const int s1 = s0 + 64;
  const int r0 = s0 >> 2, c0 = (s0 & 3) ^ (r0 & 3);
  const int r1 = s1 >> 2, c1 = (s1 & 3) ^ (r1 & 3);
  const unsigned short* gA0 = A + (size_t)(bm + r0) * K + c0 * 8;
  const unsigned short* gA1 = A + (size_t)(bm + r1) * K + c1 * 8;
  const unsigned short* gB0 = Bt + (size_t)(bn + r0) * K + c0 * 8;
  const unsigned short* gB1 = Bt + (size_t)(bn + r1) * K + c1 * 8;
  unsigned short* lA0 = As + (w * 128) * 8;
  unsigned short* lA1 = As + (w * 128 + 64) * 8;
  unsigned short* lB0 = Bs + (w * 128) * 8;
  unsigned short* lB1 = Bs + (w * 128 + 64) * 8;

  // fragment LDS addresses (k0-invariant): row r, chunk quad^(r&3)
  const int sw = quad ^ (m16 & 3);   // (r&3)==(m16&3) since tile bases are multiples of 16
  const short8* pA[4];
  const short8* pB[4];
#pragma unroll
  for (int i = 0; i < 4; ++i) {
    const int ra = wr * 64 + i * 16 + m16;
    const int rb = wc * 64 + i * 16 + m16;
    pA[i] = (const short8*)(As + ra * 32 + sw * 8);
    pB[i] = (const short8*)(Bs + rb * 32 + sw * 8);
  }

  f32x4 acc[4][4];
#pragma unroll
  for (int i = 0; i < 4; ++i)
#pragma unroll
    for (int j = 0; j < 4; ++j) { acc[i][j][0] = 0.f; acc[i][j][1] = 0.f; acc[i][j][2] = 0.f; acc[i][j][3] = 0.f; }

  for (int k0 = 0; k0 < K; k0 += 32) {
    async_cp16(gA0 + k0, lA0);
    async_cp16(gA1 + k0, lA1);
    async_cp16(gB0 + k0, lB0);
    async_cp16(gB1 + k0, lB1);
    __syncthreads();   // drains vmcnt: LDS staging complete
    short8 af[4], bfr[4];
#pragma unroll
    for (int i = 0; i < 4; ++i) { af[i] = *pA[i]; bfr[i] = *pB[i]; }
#pragma unroll
    for (int i = 0; i < 4; ++i)
#pragma unroll
      for (int j = 0; j < 4; ++j)
        acc[i][j] = __builtin_amdgcn_mfma_f32_16x16x32_bf16(af[i], bfr[j], acc[i][j], 0, 0, 0);
    __syncthreads();   // all reads done before next stage overwrites
  }

  if (mode == 0) {
#pragma unroll
    for (int j = 0; j < 4; ++j) {
      const int n = bn + wc * 64 + j * 16 + m16;
      const float bj = bias[n];
#pragma unroll
      for (int i = 0; i < 4; ++i) {
        const int mrow = bm + wr * 64 + i * 16 + quad * 4;
#pragma unroll
        for (int r2 = 0; r2 < 4; ++r2)
          C[(size_t)(mrow + r2) * N + n] = acc[i][j][r2] + bj;
      }
    }
  } else {
    // QKV epilogue: segment decode (wave-uniform: col base is 64-aligned, 768 % 64 == 0)
    const int segbase = bn + wc * 64;
    const int which = segbase / D_;
    const int h = (segbase - which * D_) >> 6;
    unsigned short* dstT = (which == 0) ? qp : (which == 1) ? kp : vp;
    float bj[4];
#pragma unroll
    for (int og = 0; og < 4; ++og) bj[og] = bias[segbase + og * 16 + m16];
    // RoPE inv freqs: d = og*16+m16, idx = d&31 -> m16 (og even) or 16+m16 (og odd)
    const float invfA = exp2f(-(float)m16 * kLog2_10000_div32);
    const float invfB = exp2f(-(float)(16 + m16) * kLog2_10000_div32);

#pragma unroll
    for (int i = 0; i < 4; ++i) {
      const int mrow = bm + wr * 64 + i * 16 + quad * 4;
#pragma unroll
      for (int r2 = 0; r2 < 4; ++r2) {
        const int m = mrow + r2;
        const int bi = m >> 11;
        const int li = m & (L_ - 1);
        float vals[4];
#pragma unroll
        for (int og = 0; og < 4; ++og) vals[og] = acc[i][og][r2] + bj[og];
        unsigned short* drow = dstT + (((size_t)(bi * H_ + h)) * L_ + li) * HD_;
        if (which == 2) {
#pragma unroll
          for (int og = 0; og < 4; ++og) drow[og * 16 + m16] = f2bf(vals[og]);
        } else {
          const float fl = (float)li;
#pragma unroll
          for (int og = 0; og < 4; ++og) {
            const int d = og * 16 + m16;
            const float theta = fl * ((og & 1) ? invfB : invfA);
            float sv, cv;
            __sincosf(theta, &sv, &cv);
            const float part = vals[og ^ 2];          // pre-rope partner at d^32
            const float rot = (og < 2) ? -part : part;  // rotate_half sign
            drow[d] = f2bf(vals[og] * cv + rot * sv);
          }
        }
      }
    }
  }
}

// ============================ Fused causal attention (MFMA bf16) ============================
__global__ __launch_bounds__(256) void attn_mfma_kernel(
    const unsigned short* __restrict__ qb, const unsigned short* __restrict__ kb,
    const unsigned short* __restrict__ vt, float* __restrict__ probs,
    unsigned short* __restrict__ attnb)
{
  __shared__ __align__(16) unsigned short Ks[64][72];      // [kpos][d]
  __shared__ __align__(16) unsigned short Vs[64][72];      // [d][kpos]
  __shared__ __align__(16) unsigned short Pb[4][16][72];   // per-wave P tile

  const int tid  = threadIdx.x;
  const int w    = tid >> 6;
  const int lane = tid & 63;
  const int m16  = lane & 15;
  const int quad = lane >> 4;

  const int bh = blockIdx.y;
  const int qt = (int)gridDim.x - 1 - (int)blockIdx.x;   // big tiles first
  const int q0 = qt * 64;
  const int bb = bh / H_;
  const int hh = bh - bb * H_;
  const int ktiles = qt + 1;
  const int qrow_base = q0 + w * 16;

  const unsigned short* kbase = kb + (size_t)bh * L_ * HD_;
  const unsigned short* vbase = vt + (size_t)bh * HD_ * L_;

  const unsigned short* qp = qb + ((size_t)bh * L_ + qrow_base + m16) * HD_ + quad * 8;
  const short8 qf0 = *(const short8*)(qp);
  const short8 qf1 = *(const short8*)(qp + 32);

  const int srow = tid >> 2;
  const int scol = (tid & 3) * 16;

  // ---------------- pass 1: row sums ----------------
  float lsum[4] = {0.f, 0.f, 0.f, 0.f};
  for (int kt = 0; kt < ktiles; ++kt) {
    const int k0 = kt * 64;
    __syncthreads();
    {
      const unsigned short* src = kbase + (size_t)(k0 + srow) * HD_ + scol;
      *(uint4*)&Ks[srow][scol]     = *(const uint4*)src;
      *(uint4*)&Ks[srow][scol + 8] = *(const uint4*)(src + 8);
    }
    __syncthreads();
#pragma unroll
    for (int cg = 0; cg < 4; ++cg) {
      const short8 b0 = *(const short8*)&Ks[cg * 16 + m16][quad * 8];
      const short8 b1 = *(const short8*)&Ks[cg * 16 + m16][32 + quad * 8];
      f32x4 s = {0.f, 0.f, 0.f, 0.f};
      s = __builtin_amdgcn_mfma_f32_16x16x32_bf16(qf0, b0, s, 0, 0, 0);
      s = __builtin_amdgcn_mfma_f32_16x16x32_bf16(qf1, b1, s, 0, 0, 0);
      const int kcol = k0 + cg * 16 + m16;
#pragma unroll
      for (int r2 = 0; r2 < 4; ++r2) {
        const int qrow = qrow_base + quad * 4 + r2;
        const float e = __expf(s[r2] * kScale);
        lsum[r2] += (kcol <= qrow) ? e : 0.f;
      }
    }
  }
  float linv[4];
#pragma unroll
  for (int r2 = 0; r2 < 4; ++r2) {
    float v = lsum[r2];
    v += __shfl_xor(v, 1, 64);
    v += __shfl_xor(v, 2, 64);
    v += __shfl_xor(v, 4, 64);
    v += __shfl_xor(v, 8, 64);
    linv[r2] = 1.f / v;
  }

  // ---------------- pass 2: probs + PV ----------------
  f32x4 oacc[4];
#pragma unroll
  for (int og = 0; og < 4; ++og) { oacc[og][0]=0.f; oacc[og][1]=0.f; oacc[og][2]=0.f; oacc[og][3]=0.f; }

  for (int kt = 0; kt < ktiles; ++kt) {
    const int k0 = kt * 64;
    __syncthreads();
    {
      const unsigned short* srck = kbase + (size_t)(k0 + srow) * HD_ + scol;
      *(uint4*)&Ks[srow][scol]     = *(const uint4*)srck;
      *(uint4*)&Ks[srow][scol + 8] = *(const uint4*)(srck + 8);
      const unsigned short* srcv = vbase + (size_t)srow * L_ + k0 + scol;
      *(uint4*)&Vs[srow][scol]     = *(const uint4*)srcv;
      *(uint4*)&Vs[srow][scol + 8] = *(const uint4*)(srcv + 8);
    }
    __syncthreads();
#pragma unroll
    for (int cg = 0; cg < 4; ++cg) {
      const short8 b0 = *(const short8*)&Ks[cg * 16 + m16][quad * 8];
      const short8 b1 = *(const short8*)&Ks[cg * 16 + m16][32 + quad * 8];
      f32x4 s = {0.f, 0.f, 0.f, 0.f};
      s = __builtin_amdgcn_mfma_f32_16x16x32_bf16(qf0, b0, s, 0, 0, 0);
      s = __builtin_amdgcn_mfma_f32_16x16x32_bf16(qf1, b1, s, 0, 0, 0);
      const int kcol = k0 + cg * 16 + m16;
#pragma unroll
      for (int r2 = 0; r2 < 4; ++r2) {
        const int qrow = qrow_base + quad * 4 + r2;
        const float p = (kcol <= qrow) ? __expf(s[r2] * kScale) * linv[r2] : 0.f;
        probs[((size_t)bh * L_ + qrow) * L_ + kcol] = p;
        Pb[w][quad * 4 + r2][cg * 16 + m16] = f2bf(p);
      }
    }
    const short8 pa0 = *(const short8*)&Pb[w][m16][quad * 8];
    const short8 pa1 = *(const short8*)&Pb[w][m16][32 + quad * 8];
#pragma unroll
    for (int og = 0; og < 4; ++og) {
      const short8 v0 = *(const short8*)&Vs[og * 16 + m16][quad * 8];
      const short8 v1 = *(const short8*)&Vs[og * 16 + m16][32 + quad * 8];
      oacc[og] = __builtin_amdgcn_mfma_f32_16x16x32_bf16(pa0, v0, oacc[og], 0, 0, 0);
      oacc[og] = __builtin_amdgcn_mfma_f32_16x16x32_bf16(pa1, v1, oacc[og], 0, 0, 0);
    }
  }

  // zero-fill masked probs columns beyond processed tiles
  {
    const float4 z4 = make_float4(0.f, 0.f, 0.f, 0.f);
#pragma unroll
    for (int r2 = 0; r2 < 4; ++r2) {
      float* pr = probs + ((size_t)bh * L_ + qrow_base + quad * 4 + r2) * L_;
      for (int c0 = ktiles * 64; c0 < L_; c0 += 64)
        *(float4*)(pr + c0 + m16 * 4) = z4;
    }
  }

  // O epilogue -> attn [B,L,D] bf16 (feeds out-proj GEMM directly)
#pragma unroll
  for (int og = 0; og < 4; ++og)
#pragma unroll
    for (int r2 = 0; r2 < 4; ++r2)
      attnb[((size_t)bb * L_ + qrow_base + quad * 4 + r2) * D_ + hh * HD_ + og * 16 + m16] =
          f2bf(oacc[og][r2]);
}

// ============================ launcher ============================
extern "C" void kernel_launch(void* const* d_in, const int* in_sizes, int n_in,
                              void* d_out, int out_size, void* d_ws, size_t ws_size,
                              hipStream_t stream)
{
  const float* x     = (const float*)d_in[0];
  const float* w_qkv = (const float*)d_in[1];
  const float* b_qkv = (const float*)d_in[2];
  const float* w_out = (const float*)d_in[3];
  const float* b_out = (const float*)d_in[4];

  float* out   = (float*)d_out;
  float* probs = out + OUT_ELEMS;

  const size_t NE = (size_t)B_ * H_ * L_ * HD_;   // 3145728
  unsigned short* qbw   = (unsigned short*)d_ws;  // bf16 q [B,H,L,64]
  unsigned short* kbw   = qbw + NE;
  unsigned short* vbw   = kbw + NE;
  unsigned short* vtw   = vbw + NE;               // v^T [B,H,64,L]
  unsigned short* xbw   = vtw + NE;               // bf16 x [M,K]
  unsigned short* attnb = xbw + NE;               // bf16 attn [B,L,D]
  unsigned short* wqT   = attnb + NE;             // bf16 w_qkv^T [2304,768]
  unsigned short* woT   = wqT + (size_t)N3_ * D_; // bf16 w_out^T [768,768]
  // total: 6*6.29MB + 3.54MB + 1.18MB = 42.5 MB

  // 1) conversions (independent)
  bf16conv_kernel<<<(int)(OUT_ELEMS / 8 / 256), 256, 0, stream>>>(x, xbw);
  wtrans_kernel<<<dim3(N3_ / 64, D_ / 64), 256, 0, stream>>>(w_qkv, wqT, D_, N3_);
  wtrans_kernel<<<dim3(D_ / 64, D_ / 64), 256, 0, stream>>>(w_out, woT, D_, D_);

  // 2) QKV projection (MFMA) + bias + fused RoPE + head-split -> bf16 q/k/v
  gemm_mfma_kernel<<<dim3(N3_ / 128, M_ / 128), 256, 0, stream>>>(
      xbw, wqT, b_qkv, nullptr, M_, N3_, D_, 1, qbw, kbw, vbw);

  // 3) V transpose for PV B-operand
  vtrans_kernel<<<dim3(L_ / 64, B_ * H_), 256, 0, stream>>>(vbw, vtw);

  // 4) fused causal attention: probs + attn (bf16)
  attn_mfma_kernel<<<dim3(L_ / 64, B_ * H_), 256, 0, stream>>>(qbw, kbw, vtw, probs, attnb);

  // 5) output projection (MFMA) + bias -> fp32 out
  gemm_mfma_kernel<<<dim3(D_ / 128, M_ / 128), 256, 0, stream>>>(
      attnb, woT, b_out, out, M_, D_, D_, 0, nullptr, nullptr, nullptr);
}